// Round 5
// baseline (304.614 us; speedup 1.0000x reference)
//
#include <hip/hip_runtime.h>
#include <cmath>

#define LL 2048
#define NROW 8192
#define DMODEL 1024
#define DINNER 2048
#define NSTATE 16
#define NSEG 64
#define SEGLEN 32   // NSEG * SEGLEN == LL

typedef unsigned short u16;
typedef __attribute__((ext_vector_type(8))) unsigned short u16x8;
typedef __attribute__((ext_vector_type(8))) short short8;
typedef __attribute__((ext_vector_type(4))) float floatx4;
typedef __attribute__((ext_vector_type(16))) float floatx16;

__device__ __forceinline__ float bf2f(u16 h) {
    unsigned u = ((unsigned)h) << 16;
    float f;
    __builtin_memcpy(&f, &u, 4);
    return f;
}
__device__ __forceinline__ u16 f2bf(float f) {
    unsigned u;
    __builtin_memcpy(&u, &f, 4);
    u = u + 0x7fffu + ((u >> 16) & 1u);
    return (u16)(u >> 16);
}
__device__ __forceinline__ float silu_f(float x) { return x / (1.f + __expf(-x)); }

// One kernel converts all six fp32->bf16 tensors (2048 elems per block).
__global__ __launch_bounds__(256) void cvt_multi(
    const float* __restrict__ s0, const float* __restrict__ s1,
    const float* __restrict__ s2, const float* __restrict__ s3,
    const float* __restrict__ s4, const float* __restrict__ s5,
    u16* __restrict__ d0, u16* __restrict__ d1, u16* __restrict__ d2,
    u16* __restrict__ d3, u16* __restrict__ d4, u16* __restrict__ d5) {
    int bid = blockIdx.x;
    const float* s;
    u16* d;
    size_t off;
    if (bid < 4096)      { s = s0; d = d0; off = (size_t)bid * 2048; }
    else if (bid < 6144) { s = s1; d = d1; off = (size_t)(bid - 4096) * 2048; }
    else if (bid < 7168) { s = s2; d = d2; off = (size_t)(bid - 6144) * 2048; }
    else if (bid < 7184) { s = s3; d = d3; off = (size_t)(bid - 7168) * 2048; }
    else if (bid < 7200) { s = s4; d = d4; off = (size_t)(bid - 7184) * 2048; }
    else                 { s = s5; d = d5; off = (size_t)(bid - 7200) * 2048; }
    size_t i = off + (size_t)threadIdx.x * 8;
    float4 a = *(const float4*)&s[i];
    float4 b = *(const float4*)&s[i + 4];
    u16x8 o;
    o[0] = f2bf(a.x); o[1] = f2bf(a.y); o[2] = f2bf(a.z); o[3] = f2bf(a.w);
    o[4] = f2bf(b.x); o[5] = f2bf(b.y); o[6] = f2bf(b.z); o[7] = f2bf(b.w);
    *(u16x8*)&d[i] = o;
}

#define GL_LDS(gp, lp)                                                        \
    __builtin_amdgcn_global_load_lds(                                         \
        (const __attribute__((address_space(1))) void*)(gp),                  \
        (__attribute__((address_space(3))) void*)(lp), 16, 0, 0)
#define BAR() __builtin_amdgcn_s_barrier()
#define SB0() __builtin_amdgcn_sched_barrier(0)
#define LGKM0()                                                               \
    do {                                                                      \
        asm volatile("s_waitcnt lgkmcnt(0)" ::: "memory");                    \
        __builtin_amdgcn_sched_barrier(0);                                    \
    } while (0)
#define VMC4() asm volatile("s_waitcnt vmcnt(4)" ::: "memory")
#define PRIO1() __builtin_amdgcn_s_setprio(1)
#define PRIO0() __builtin_amdgcn_s_setprio(0)

// ---------------------------------------------------------------------------
// 256x256 GEMM (C = A @ B^T), reads-after-MFMA pipelined 4-phase schedule,
// inner op = 32x32x16 bf16 MFMA (4061 FLOP/cyc vs 3378 for 16x16x32; half
// the issue slots). Per-wave C = 128x64 as 4x2 of 32x32 frags.
// Fragment mapping (verified in gemm_bt_mfma, m74/m101): A/B operand row =
// lane&31, 8-elem k-block = lane>>5; C/D col = lane&31,
// row = (r&3) + 8*(r>>2) + 4*(lane>>5).
// LDS layout/staging/swizzle identical to R4 (slot = g ^ (row&7), staging
// pre-swizzled source; 0 bank conflicts measured R1/R3/R4).
// Schedule per K-tile (BK=64), phases = (miHalf x ni), 8 MFMA each:
//  ph1: lgkm0 MFMA(afX,bf0->acc[0..1][0]); read bf1(cur);  stage A0(t+1)
//  ph2: lgkm0 MFMA(afX,bf1->acc[0..1][1]); read afY(cur);  stage A1(t+1)
//       vmcnt(4) [B(t+1) landed] BAR
//  ph3: lgkm0 MFMA(afY,bf0->acc[2..3][0]); read bf0(nxt);  stage B0(t+2)
//  ph4:       MFMA(afY,bf1->acc[2..3][1]);                 stage B1(t+2)
//       vmcnt(4) [A(t+1) landed] BAR; read afX(nxt)
// 2 barriers/tile, never vmcnt(0) in the loop. Staging pointers run up to
// 2 tiles past K-end into the adjacent workspace buffer (valid memory,
// dead LDS buffer) -- callers guarantee A,B are followed by readable
// allocations (xb->wb, wb->owb).
// XCD-aware bijective block swizzle (grid % 8 == 0).
// ---------------------------------------------------------------------------
template <int OUT_BF16>
__global__ __launch_bounds__(512, 2) void gemm_bt_256(
    const u16* __restrict__ A, const u16* __restrict__ B,
    void* __restrict__ Cout, int N, int K) {
    __shared__ u16 sAf[2 * 2 * 128 * 64];   // [buf][half][row*64 + slot*8]
    __shared__ u16 sBf[2 * 2 * 128 * 64];
    const int tid = threadIdx.x;
    const int lane = tid & 63;
    const int wave = tid >> 6;   // 0..7
    const int wm = wave >> 2;    // 0..1
    const int wn = wave & 3;     // 0..3

    // XCD swizzle: linearize grid, chunk per XCD (nwg % 8 == 0 here).
    const int gx = gridDim.x;
    const int nwg = gx * gridDim.y;
    const int cpx = nwg >> 3;
    int lin = blockIdx.y * gx + blockIdx.x;
    int swz = (lin & 7) * cpx + (lin >> 3);
    const int bm = (swz / gx) * 256;
    const int bn = (swz % gx) * 256;

    // ---- staging addresses (pre-swizzled source k-slot) ----
    const int gslot = (lane & 7) ^ ((lane >> 3) & 7);
    const int srowoff = lane >> 3;                  // 0..7
    const u16* aStage = A + (size_t)(bm + wave * 8 + srowoff) * K + gslot * 8 + 64;
    const u16* bStage = B + (size_t)(bn + wave * 8 + srowoff) * K + gslot * 8 + 128;
    const size_t row64 = (size_t)64 * K;
    const size_t row128 = (size_t)128 * K;

#define STAGE_A(BUF, H, PTR)                                                  \
    do {                                                                      \
        GL_LDS((PTR) + (H) * row128,         &sAf[(BUF) * 16384 + (H) * 8192 + wave * 512]); \
        GL_LDS((PTR) + (H) * row128 + row64, &sAf[(BUF) * 16384 + (H) * 8192 + (8 + wave) * 512]); \
    } while (0)
#define STAGE_B(BUF, H, PTR)                                                  \
    do {                                                                      \
        GL_LDS((PTR) + (H) * row128,         &sBf[(BUF) * 16384 + (H) * 8192 + wave * 512]); \
        GL_LDS((PTR) + (H) * row128 + row64, &sBf[(BUF) * 16384 + (H) * 8192 + (8 + wave) * 512]); \
    } while (0)

    // ---- fragment read bases: op row = lane&31, k-block = lane>>5 ----
    const int fcol = lane & 31;
    const int khalf = lane >> 5;
    int aS[4];
#pragma unroll
    for (int ks = 0; ks < 4; ++ks) aS[ks] = ((ks * 2 + khalf) ^ (fcol & 7)) * 8;
    const int aRow = wm * 8192 + fcol * 64;
    const int bRow = (wn >> 1) * 8192 + ((wn & 1) * 64 + fcol) * 64;

#define RD_A2(dst, BUF, R0)                                                   \
    do {                                                                      \
        _Pragma("unroll")                                                     \
        for (int m = 0; m < 2; ++m)                                           \
            _Pragma("unroll")                                                 \
            for (int ks = 0; ks < 4; ++ks)                                    \
                dst[m][ks] = *(const short8*)&sAf[(BUF) * 16384 + aRow +      \
                                                  ((R0) + m * 32) * 64 + aS[ks]]; \
    } while (0)
#define RD_B1(dst, BUF, NI)                                                   \
    do {                                                                      \
        _Pragma("unroll")                                                     \
        for (int ks = 0; ks < 4; ++ks)                                        \
            dst[ks] = *(const short8*)&sBf[(BUF) * 16384 + bRow +             \
                                           (NI) * 32 * 64 + aS[ks]];          \
    } while (0)
#define MFMA8(AF, MB, BF, NI)                                                 \
    do {                                                                      \
        _Pragma("unroll")                                                     \
        for (int ks = 0; ks < 4; ++ks)                                        \
            _Pragma("unroll")                                                 \
            for (int m = 0; m < 2; ++m)                                       \
                acc[(MB) + m][NI] = __builtin_amdgcn_mfma_f32_32x32x16_bf16(  \
                    AF[m][ks], BF[ks], acc[(MB) + m][NI], 0, 0, 0);           \
    } while (0)

    floatx16 acc[4][2];
#pragma unroll
    for (int i = 0; i < 4; ++i)
#pragma unroll
        for (int j = 0; j < 2; ++j) acc[i][j] = (floatx16)(0.f);

    short8 afX[2][4], afY[2][4], bf0[4], bf1[4];

    // ---- prologue: stage A(0),B(0),B(1); vmcnt(4) leaves B(1) in flight ----
    {
        const u16* a0 = aStage - 64;
        const u16* b0 = bStage - 128;
        STAGE_A(0, 0, a0);
        STAGE_A(0, 1, a0);
        STAGE_B(0, 0, b0);
        STAGE_B(0, 1, b0);
        STAGE_B(1, 0, b0 + 64);
        STAGE_B(1, 1, b0 + 64);
    }
    VMC4();
    BAR();
    RD_A2(afX, 0, 0);
    RD_B1(bf0, 0, 0);
    SB0();

// TILE body; CUR/NXT compile-time via x2 unroll.
#define TILE(CUR, NXT)                                                        \
    /* ph1: MFMA (mi01, ni0); read bf1(cur); stage A0(t+1) */                 \
    LGKM0();                                                                  \
    PRIO1();                                                                  \
    MFMA8(afX, 0, bf0, 0);                                                    \
    PRIO0();                                                                  \
    SB0();                                                                    \
    RD_B1(bf1, CUR, 1);                                                       \
    STAGE_A(NXT, 0, aStage);                                                  \
    SB0();                                                                    \
    /* ph2: MFMA (mi01, ni1); read afY(cur); stage A1(t+1); mid sync */       \
    LGKM0();                                                                  \
    PRIO1();                                                                  \
    MFMA8(afX, 0, bf1, 1);                                                    \
    PRIO0();                                                                  \
    SB0();                                                                    \
    RD_A2(afY, CUR, 64);                                                      \
    STAGE_A(NXT, 1, aStage);                                                  \
    VMC4(); /* B(t+1) landed */                                               \
    BAR();                                                                    \
    /* ph3: MFMA (mi23, ni0); read bf0'(nxt); stage B0(t+2) */                \
    LGKM0();                                                                  \
    PRIO1();                                                                  \
    MFMA8(afY, 2, bf0, 0);                                                    \
    PRIO0();                                                                  \
    SB0();                                                                    \
    RD_B1(bf0, NXT, 0);                                                       \
    STAGE_B(CUR, 0, bStage);                                                  \
    SB0();                                                                    \
    /* ph4: MFMA (mi23, ni1); stage B1(t+2); end sync; read afX'(nxt) */      \
    PRIO1();                                                                  \
    MFMA8(afY, 2, bf1, 1);                                                    \
    PRIO0();                                                                  \
    SB0();                                                                    \
    STAGE_B(CUR, 1, bStage);                                                  \
    VMC4(); /* A(t+1) landed */                                               \
    BAR();                                                                    \
    RD_A2(afX, NXT, 0);                                                       \
    SB0();                                                                    \
    aStage += 64;                                                             \
    bStage += 64;

    const int NT = K >> 6;  // even (16 here)
    for (int t = 0; t < NT; t += 2) {
        TILE(0, 1)
        TILE(1, 0)
    }
#undef TILE

    // epilogue: C/D 32x32 layout: col = lane&31,
    // row = (r&3) + 8*(r>>2) + 4*(lane>>5)
    const int erow = 4 * khalf;
#pragma unroll
    for (int mi = 0; mi < 4; ++mi)
#pragma unroll
        for (int ni = 0; ni < 2; ++ni)
#pragma unroll
            for (int r = 0; r < 16; ++r) {
                int grow = bm + wm * 128 + mi * 32 + (r & 3) + 8 * (r >> 2) + erow;
                int gcol = bn + wn * 64 + ni * 32 + fcol;
                float v = acc[mi][ni][r];
                if (OUT_BF16)
                    ((u16*)Cout)[(size_t)grow * N + gcol] = f2bf(v);
                else
                    ((float*)Cout)[(size_t)grow * N + gcol] = v;
            }
#undef STAGE_A
#undef STAGE_B
#undef RD_A2
#undef RD_B1
#undef MFMA8
}

// C[m][n] = sum_k A[m,k]*B[n,k]; A: MxK bf16, B: NxK bf16, row-major.
// 128x128 tile, BK=32, 4 waves (2x2), each wave 64x64 via 2x2 of 32x32x16 MFMA
// (2 K-steps per BK). Kept for the thin out-proj GEMM (N=1024: 512 blocks).
// + XCD-aware bijective block swizzle when grid % 8 == 0.
template <int OUT_BF16>
__global__ __launch_bounds__(256) void gemm_bt_mfma(
    const u16* __restrict__ A, const u16* __restrict__ B,
    void* __restrict__ Cout, int N, int K) {
    __shared__ u16 As[128 * 32];
    __shared__ u16 Bs[128 * 32];
    const int tid = threadIdx.x;
    const int lane = tid & 63;
    const int wave = tid >> 6;

    const int gx = gridDim.x;
    const int nwg = gx * gridDim.y;
    int lin = blockIdx.y * gx + blockIdx.x;
    if ((nwg & 7) == 0) {
        int cpx = nwg >> 3;
        lin = (lin & 7) * cpx + (lin >> 3);
    }
    const int bm = (lin / gx) * 128;
    const int bn = (lin % gx) * 128;

    const int kbg = (lane & 3) ^ ((lane >> 3) & 3);
    const int srow = lane >> 2;
    const u16* ag[2];
    const u16* bg[2];
#pragma unroll
    for (int p = 0; p < 2; ++p) {
        int c = wave * 2 + p;
        ag[p] = A + (size_t)(bm + c * 16 + srow) * K + kbg * 8;
        bg[p] = B + (size_t)(bn + c * 16 + srow) * K + kbg * 8;
    }
    const int frow = lane & 31;
    const int khi = lane >> 5;
    const int wr = (wave >> 1) * 64;
    const int wc = (wave & 1) * 64;
    int aoff[2][2], boff[2][2];
#pragma unroll
    for (int mi = 0; mi < 2; ++mi)
#pragma unroll
        for (int kh = 0; kh < 2; ++kh) {
            int rA = wr + mi * 32 + frow;
            int rB = wc + mi * 32 + frow;
            int kb = kh * 2 + khi;
            aoff[mi][kh] = rA * 32 + (kb ^ ((rA >> 1) & 3)) * 8;
            boff[mi][kh] = rB * 32 + (kb ^ ((rB >> 1) & 3)) * 8;
        }
    floatx16 acc[2][2];
#pragma unroll
    for (int i = 0; i < 2; ++i)
#pragma unroll
        for (int j = 0; j < 2; ++j) acc[i][j] = (floatx16)(0.f);

    for (int k0 = 0; k0 < K; k0 += 32) {
        __syncthreads();
#pragma unroll
        for (int p = 0; p < 2; ++p) {
            int c = wave * 2 + p;
            __builtin_amdgcn_global_load_lds(
                (const __attribute__((address_space(1))) void*)ag[p],
                (__attribute__((address_space(3))) void*)&As[c * 512], 16, 0, 0);
            __builtin_amdgcn_global_load_lds(
                (const __attribute__((address_space(1))) void*)bg[p],
                (__attribute__((address_space(3))) void*)&Bs[c * 512], 16, 0, 0);
            ag[p] += 32;
            bg[p] += 32;
        }
        __syncthreads();
        short8 af[2][2], bf[2][2];
#pragma unroll
        for (int mi = 0; mi < 2; ++mi)
#pragma unroll
            for (int kh = 0; kh < 2; ++kh) {
                af[mi][kh] = *(const short8*)&As[aoff[mi][kh]];
                bf[mi][kh] = *(const short8*)&Bs[boff[mi][kh]];
            }
#pragma unroll
        for (int kh = 0; kh < 2; ++kh)
#pragma unroll
            for (int mi = 0; mi < 2; ++mi)
#pragma unroll
                for (int ni = 0; ni < 2; ++ni)
                    acc[mi][ni] = __builtin_amdgcn_mfma_f32_32x32x16_bf16(
                        af[mi][kh], bf[ni][kh], acc[mi][ni], 0, 0, 0);
    }
    // C/D layout (m74/m101): col = lane&31, row = (reg&3) + 8*(reg>>2) + 4*(lane>>5)
    const int cc = lane & 31;
    const int rbase = 4 * (lane >> 5);
#pragma unroll
    for (int mi = 0; mi < 2; ++mi)
#pragma unroll
        for (int ni = 0; ni < 2; ++ni)
#pragma unroll
            for (int r = 0; r < 16; ++r) {
                int grow = bm + wr + mi * 32 + (r & 3) + 8 * (r >> 2) + rbase;
                int gcol = bn + wc + ni * 32 + cc;
                float v = acc[mi][ni][r];
                if (OUT_BF16)
                    ((u16*)Cout)[(size_t)grow * N + gcol] = f2bf(v);
                else
                    ((float*)Cout)[(size_t)grow * N + gcol] = v;
            }
}

// depthwise causal conv (DC=4) + bias + silu + row-mean.
__global__ __launch_bounds__(256) void conv_silu_avg(
    const u16* __restrict__ xin, const float* __restrict__ cw,
    const float* __restrict__ cb, u16* __restrict__ xconv,
    float* __restrict__ xavg) {
    const int blk = blockIdx.x;        // 512 blocks
    const int b = blk >> 7;
    const int lc = blk & 127;
    const int row0 = b * LL + lc * 16;
    const int tid = threadIdx.x;
    const int lane = tid & 63, wave = tid >> 6;
    const int d0 = tid * 8;
    float4 cwv[8];
    float cbv[8];
#pragma unroll
    for (int e = 0; e < 8; ++e) cwv[e] = *(const float4*)&cw[(d0 + e) * 4];
#pragma unroll
    for (int e = 0; e < 8; e += 4) {
        float4 c = *(const float4*)&cb[d0 + e];
        cbv[e] = c.x; cbv[e + 1] = c.y; cbv[e + 2] = c.z; cbv[e + 3] = c.w;
    }
    u16x8 w0, w1, w2;
    if (lc == 0) {
        w0 = (u16x8)0; w1 = (u16x8)0; w2 = (u16x8)0;
    } else {
        w0 = *(const u16x8*)&xin[(size_t)(row0 - 3) * (2 * DINNER) + d0];
        w1 = *(const u16x8*)&xin[(size_t)(row0 - 2) * (2 * DINNER) + d0];
        w2 = *(const u16x8*)&xin[(size_t)(row0 - 1) * (2 * DINNER) + d0];
    }
    float sums[16];
#pragma unroll
    for (int t = 0; t < 16; ++t) {
        u16x8 cur = *(const u16x8*)&xin[(size_t)(row0 + t) * (2 * DINNER) + d0];
        float lsum = 0.f;
        u16x8 o;
#pragma unroll
        for (int e = 0; e < 8; ++e) {
            float acc = cbv[e];
            acc += bf2f(w0[e]) * cwv[e].x;
            acc += bf2f(w1[e]) * cwv[e].y;
            acc += bf2f(w2[e]) * cwv[e].z;
            acc += bf2f(cur[e]) * cwv[e].w;
            float s = silu_f(acc);
            lsum += s;
            o[e] = f2bf(s);
        }
        *(u16x8*)&xconv[(size_t)(row0 + t) * DINNER + d0] = o;
        sums[t] = lsum;
        w0 = w1; w1 = w2; w2 = cur;
    }
#pragma unroll
    for (int off = 32; off; off >>= 1)
#pragma unroll
        for (int t = 0; t < 16; ++t) sums[t] += __shfl_down(sums[t], off);
    __shared__ float wred[4][16];
    if (lane == 0) {
#pragma unroll
        for (int t = 0; t < 16; ++t) wred[wave][t] = sums[t];
    }
    __syncthreads();
    if (tid < 16)
        xavg[row0 + tid] = (wred[0][tid] + wred[1][tid] + wred[2][tid] + wred[3][tid]) *
                           (1.f / DINNER);
}

// delta/B/C projections: thin GEMM (8192 x 48 x 2048), K split across waves.
__global__ __launch_bounds__(256) void dbc_direct(
    const u16* __restrict__ xconv, const u16* __restrict__ wcat,
    const float* __restrict__ db, const float* __restrict__ A_log,
    const float* __restrict__ xavg,
    float* __restrict__ a_out, float* __restrict__ u_out, float* __restrict__ c_out) {
    __shared__ float part[4][32][48];
    const int tid = threadIdx.x;
    const int lane = tid & 63;
    const int wave = tid >> 6;
    const int bm = blockIdx.x * 32;
    const int fr = lane & 15;
    const int kq = lane >> 4;
    const int k0 = wave * 512 + kq * 8;

    const u16* ap0 = xconv + (size_t)(bm + fr) * DINNER + k0;
    const u16* ap1 = xconv + (size_t)(bm + 16 + fr) * DINNER + k0;
    const u16* bp0 = wcat + (size_t)(fr) * DINNER + k0;
    const u16* bp1 = wcat + (size_t)(16 + fr) * DINNER + k0;
    const u16* bp2 = wcat + (size_t)(32 + fr) * DINNER + k0;

    floatx4 acc[2][3];
#pragma unroll
    for (int mi = 0; mi < 2; ++mi)
#pragma unroll
        for (int ni = 0; ni < 3; ++ni) acc[mi][ni] = (floatx4){0.f, 0.f, 0.f, 0.f};

#pragma unroll 4
    for (int kk = 0; kk < 16; ++kk) {
        short8 a0 = *(const short8*)ap0;
        short8 a1 = *(const short8*)ap1;
        short8 b0 = *(const short8*)bp0;
        short8 b1 = *(const short8*)bp1;
        short8 b2 = *(const short8*)bp2;
        ap0 += 32; ap1 += 32; bp0 += 32; bp1 += 32; bp2 += 32;
        acc[0][0] = __builtin_amdgcn_mfma_f32_16x16x32_bf16(a0, b0, acc[0][0], 0, 0, 0);
        acc[0][1] = __builtin_amdgcn_mfma_f32_16x16x32_bf16(a0, b1, acc[0][1], 0, 0, 0);
        acc[0][2] = __builtin_amdgcn_mfma_f32_16x16x32_bf16(a0, b2, acc[0][2], 0, 0, 0);
        acc[1][0] = __builtin_amdgcn_mfma_f32_16x16x32_bf16(a1, b0, acc[1][0], 0, 0, 0);
        acc[1][1] = __builtin_amdgcn_mfma_f32_16x16x32_bf16(a1, b1, acc[1][1], 0, 0, 0);
        acc[1][2] = __builtin_amdgcn_mfma_f32_16x16x32_bf16(a1, b2, acc[1][2], 0, 0, 0);
    }
    // C/D 16x16 layout: col = lane&15, row = (lane>>4)*4 + r
    const int cr = kq * 4;
#pragma unroll
    for (int mi = 0; mi < 2; ++mi)
#pragma unroll
        for (int ni = 0; ni < 3; ++ni)
#pragma unroll
            for (int r = 0; r < 4; ++r)
                part[wave][mi * 16 + cr + r][ni * 16 + fr] = acc[mi][ni][r];
    __syncthreads();
#pragma unroll
    for (int it = tid; it < 512; it += 256) {
        int row = it >> 4;
        int s = it & 15;
        float sd = 0.f, sb = 0.f, sc = 0.f;
#pragma unroll
        for (int w = 0; w < 4; ++w) {
            sd += part[w][row][s];
            sb += part[w][row][s + 16];
            sc += part[w][row][s + 32];
        }
        int grow = bm + row;
        float Aa = -__expf(A_log[s]);
        float pre = sd + db[s];
        float delta = (pre > 20.f) ? pre : log1pf(__expf(pre));
        a_out[grow * NSTATE + s] = __expf(delta * Aa);
        u_out[grow * NSTATE + s] = delta * sb * xavg[grow];
        c_out[grow * NSTATE + s] = sc;
    }
}

// ---- fused parallel linear scan: one kernel, 4 blocks (one per batch) ----
__global__ __launch_bounds__(1024) void scan_fused(
    const float* __restrict__ a, const float* __restrict__ u,
    const float* __restrict__ c, float* __restrict__ y) {
    const int b = blockIdx.x;
    const int tid = threadIdx.x;
    const int s = tid & 15;
    const int seg = tid >> 4;   // 0..63
    __shared__ float Ps[NSEG][NSTATE];
    __shared__ float Hs[NSEG][NSTATE];
    __shared__ float HSs[NSEG][NSTATE];

    size_t base = (size_t)(b * LL + seg * SEGLEN) * NSTATE + s;
    float P = 1.f, h = 0.f;
#pragma unroll 8
    for (int t = 0; t < SEGLEN; ++t) {
        float av = a[base + (size_t)t * NSTATE];
        float uv = u[base + (size_t)t * NSTATE];
        h = fmaf(av, h, uv);
        P *= av;
    }
    Ps[seg][s] = P;
    Hs[seg][s] = h;
    __syncthreads();
    if (tid < 16) {
        float hh = 0.f;
        for (int g = 0; g < NSEG; ++g) {
            HSs[g][tid] = hh;
            hh = fmaf(Ps[g][tid], hh, Hs[g][tid]);
        }
    }
    __syncthreads();
    float h2 = HSs[seg][s];
#pragma unroll 8
    for (int t = 0; t < SEGLEN; ++t) {
        float av = a[base + (size_t)t * NSTATE];
        float uv = u[base + (size_t)t * NSTATE];
        float cv = c[base + (size_t)t * NSTATE];
        h2 = fmaf(av, h2, uv);
        float p = h2 * cv;
        p += __shfl_xor(p, 1);
        p += __shfl_xor(p, 2);
        p += __shfl_xor(p, 4);
        p += __shfl_xor(p, 8);
        if (s == 0) y[b * LL + seg * SEGLEN + t] = p;
    }
}

// y_skip = y*silu(x_gate) + x_conv*D  -> bf16
__global__ __launch_bounds__(256) void gate_skip(
    const u16* __restrict__ xin, const float* __restrict__ y,
    const float* __restrict__ Dv, const u16* __restrict__ xconv,
    u16* __restrict__ yskip) {
    size_t i = ((size_t)blockIdx.x * 256 + threadIdx.x) * 8;
    int row = (int)(i >> 11);
    int d = (int)(i & (DINNER - 1));
    u16x8 g = *(const u16x8*)&xin[(size_t)row * (2 * DINNER) + DINNER + d];
    u16x8 xc = *(const u16x8*)&xconv[i];
    float yv = y[row];
    u16x8 o;
#pragma unroll
    for (int e = 0; e < 8; ++e) {
        float gv = silu_f(bf2f(g[e]));
        float v = yv * gv + bf2f(xc[e]) * Dv[d + e];
        o[e] = f2bf(v);
    }
    *(u16x8*)&yskip[i] = o;
}

extern "C" void kernel_launch(void* const* d_in, const int* in_sizes, int n_in,
                              void* d_out, int out_size, void* d_ws, size_t ws_size,
                              hipStream_t stream) {
    const float* x       = (const float*)d_in[0];
    const float* w_in    = (const float*)d_in[1];
    const float* conv_w  = (const float*)d_in[2];
    const float* conv_b  = (const float*)d_in[3];
    const float* A_log   = (const float*)d_in[4];
    const float* Dv      = (const float*)d_in[5];
    const float* delta_w = (const float*)d_in[6];
    const float* delta_b = (const float*)d_in[7];
    const float* B_w     = (const float*)d_in[8];
    const float* C_w     = (const float*)d_in[9];
    const float* out_w   = (const float*)d_in[10];
    float* out = (float*)d_out;

    u16* xb  = (u16*)d_ws;                 // 8192*1024
    u16* wb  = xb + 8388608;               // 4096*1024
    u16* owb = wb + 4194304;               // 1024*2048
    u16* wsb = owb + 2097152;              // 48*2048 (concat dw,bw,cw)
    u16* xin = wsb + 98304;                // 8192*4096
    u16* xcv = xin + 33554432;             // 8192*2048
    u16* ysk = xcv + 16777216;             // 8192*2048
    float* fb     = (float*)(ysk + 16777216);
    float* abuf   = fb;                    // 8192*16
    float* ubuf   = abuf + 131072;
    float* cbuf   = ubuf + 131072;
    float* ybuf   = cbuf + 131072;         // 8192
    float* avgbuf = ybuf + 8192;           // 8192

    cvt_multi<<<7216, 256, 0, stream>>>(x, w_in, out_w, delta_w, B_w, C_w,
                                        xb, wb, owb, wsb, wsb + 32768, wsb + 65536);

    // x_inner = x @ in_proj_w.T : (8192x1024)@(4096x1024)^T -> bf16
    gemm_bt_256<1><<<dim3(16, 32), 512, 0, stream>>>(xb, wb, xin, 2 * DINNER, DMODEL);

    conv_silu_avg<<<512, 256, 0, stream>>>(xin, conv_w, conv_b, xcv, avgbuf);
    dbc_direct<<<256, 256, 0, stream>>>(xcv, wsb, delta_b, A_log, avgbuf,
                                        abuf, ubuf, cbuf);

    scan_fused<<<4, 1024, 0, stream>>>(abuf, ubuf, cbuf, ybuf);

    gate_skip<<<NROW * DINNER / 8 / 256, 256, 0, stream>>>(xin, ybuf, Dv, xcv, ysk);

    // out = y_skip @ out_proj_w.T : (8192x2048)@(1024x2048)^T -> fp32
    gemm_bt_mfma<0><<<dim3(8, 64), 256, 0, stream>>>(ysk, owb, out, DMODEL, DINNER);
}

// Round 6
// 288.476 us; speedup vs baseline: 1.0559x; 1.0559x over previous
//
#include <hip/hip_runtime.h>
#include <cmath>

#define LL 2048
#define NROW 8192
#define DMODEL 1024
#define DINNER 2048
#define NSTATE 16
#define NSEG 64
#define SEGLEN 32   // NSEG * SEGLEN == LL

typedef unsigned short u16;
typedef __attribute__((ext_vector_type(8))) unsigned short u16x8;
typedef __attribute__((ext_vector_type(8))) short short8;
typedef __attribute__((ext_vector_type(4))) float floatx4;
typedef __attribute__((ext_vector_type(16))) float floatx16;

__device__ __forceinline__ float bf2f(u16 h) {
    unsigned u = ((unsigned)h) << 16;
    float f;
    __builtin_memcpy(&f, &u, 4);
    return f;
}
__device__ __forceinline__ u16 f2bf(float f) {
    unsigned u;
    __builtin_memcpy(&u, &f, 4);
    u = u + 0x7fffu + ((u >> 16) & 1u);
    return (u16)(u >> 16);
}
__device__ __forceinline__ float silu_f(float x) { return x / (1.f + __expf(-x)); }

// One kernel converts all six fp32->bf16 tensors (2048 elems per block).
__global__ __launch_bounds__(256) void cvt_multi(
    const float* __restrict__ s0, const float* __restrict__ s1,
    const float* __restrict__ s2, const float* __restrict__ s3,
    const float* __restrict__ s4, const float* __restrict__ s5,
    u16* __restrict__ d0, u16* __restrict__ d1, u16* __restrict__ d2,
    u16* __restrict__ d3, u16* __restrict__ d4, u16* __restrict__ d5) {
    int bid = blockIdx.x;
    const float* s;
    u16* d;
    size_t off;
    if (bid < 4096)      { s = s0; d = d0; off = (size_t)bid * 2048; }
    else if (bid < 6144) { s = s1; d = d1; off = (size_t)(bid - 4096) * 2048; }
    else if (bid < 7168) { s = s2; d = d2; off = (size_t)(bid - 6144) * 2048; }
    else if (bid < 7184) { s = s3; d = d3; off = (size_t)(bid - 7168) * 2048; }
    else if (bid < 7200) { s = s4; d = d4; off = (size_t)(bid - 7184) * 2048; }
    else                 { s = s5; d = d5; off = (size_t)(bid - 7200) * 2048; }
    size_t i = off + (size_t)threadIdx.x * 8;
    float4 a = *(const float4*)&s[i];
    float4 b = *(const float4*)&s[i + 4];
    u16x8 o;
    o[0] = f2bf(a.x); o[1] = f2bf(a.y); o[2] = f2bf(a.z); o[3] = f2bf(a.w);
    o[4] = f2bf(b.x); o[5] = f2bf(b.y); o[6] = f2bf(b.z); o[7] = f2bf(b.w);
    *(u16x8*)&d[i] = o;
}

#define GL_LDS(gp, lp)                                                        \
    __builtin_amdgcn_global_load_lds(                                         \
        (const __attribute__((address_space(1))) void*)(gp),                  \
        (__attribute__((address_space(3))) void*)(lp), 16, 0, 0)
#define BAR() __builtin_amdgcn_s_barrier()
#define SB0() __builtin_amdgcn_sched_barrier(0)
#define LGKM0()                                                               \
    do {                                                                      \
        asm volatile("s_waitcnt lgkmcnt(0)" ::: "memory");                    \
        __builtin_amdgcn_sched_barrier(0);                                    \
    } while (0)
#define VMC4() asm volatile("s_waitcnt vmcnt(4)" ::: "memory")
#define VMC2() asm volatile("s_waitcnt vmcnt(2)" ::: "memory")
#define PRIO1() __builtin_amdgcn_s_setprio(1)
#define PRIO0() __builtin_amdgcn_s_setprio(0)

// ---------------------------------------------------------------------------
// 256x256 GEMM (C = A @ B^T), reads-after-MFMA pipelined 4-phase schedule.
// (R4-verified: 72.9 us, MfmaUtil 37%, 0 bank conflicts, VGPR 128 no-spill.)
// Per phase: lgkm(0) -> MFMA x16 -> issue NEXT phase's ds_reads + 1 stage.
// 2 barriers/tile (mid + end), each preceded by counted vmcnt(4):
//   mid  (after ph2): B(t+1) landed ; end (after ph4): A(t+1) landed.
// Staging train: A(t+1) at ph1/ph2, B(t+2) at ph3/ph4. Never vmcnt(0).
// Frag regs: afX/afY + bf01/bf23 (B reused ph1+ph3 / ph2+ph4).
// Staging pointers run up to 2 tiles past K-end into the adjacent workspace
// allocation (valid memory, dead LDS buffer): callers guarantee A,B are
// followed by readable allocations (xb->wb, wb->owb).
// LDS swizzle: [128][64]-elem half-tiles, stored slot = g ^ (row&7).
// XCD-aware bijective block swizzle (grid % 8 == 0).
// ---------------------------------------------------------------------------
template <int OUT_BF16>
__global__ __launch_bounds__(512, 2) void gemm_bt_256(
    const u16* __restrict__ A, const u16* __restrict__ B,
    void* __restrict__ Cout, int N, int K) {
    __shared__ u16 sAf[2 * 2 * 128 * 64];   // [buf][half][row*64 + slot*8]
    __shared__ u16 sBf[2 * 2 * 128 * 64];
    const int tid = threadIdx.x;
    const int lane = tid & 63;
    const int wave = tid >> 6;   // 0..7
    const int wm = wave >> 2;    // 0..1
    const int wn = wave & 3;     // 0..3

    // XCD swizzle: linearize grid, chunk per XCD (nwg % 8 == 0 here).
    const int gx = gridDim.x;
    const int nwg = gx * gridDim.y;
    const int cpx = nwg >> 3;
    int lin = blockIdx.y * gx + blockIdx.x;
    int swz = (lin & 7) * cpx + (lin >> 3);
    const int bm = (swz / gx) * 256;
    const int bn = (swz % gx) * 256;

    // ---- staging addresses (pre-swizzled source k-slot) ----
    const int gslot = (lane & 7) ^ ((lane >> 3) & 7);
    const int srowoff = lane >> 3;                  // 0..7
    const u16* aStage = A + (size_t)(bm + wave * 8 + srowoff) * K + gslot * 8 + 64;
    const u16* bStage = B + (size_t)(bn + wave * 8 + srowoff) * K + gslot * 8 + 128;
    const size_t row64 = (size_t)64 * K;
    const size_t row128 = (size_t)128 * K;

#define STAGE_A(BUF, H, PTR)                                                  \
    do {                                                                      \
        GL_LDS((PTR) + (H) * row128,         &sAf[(BUF) * 16384 + (H) * 8192 + wave * 512]); \
        GL_LDS((PTR) + (H) * row128 + row64, &sAf[(BUF) * 16384 + (H) * 8192 + (8 + wave) * 512]); \
    } while (0)
#define STAGE_B(BUF, H, PTR)                                                  \
    do {                                                                      \
        GL_LDS((PTR) + (H) * row128,         &sBf[(BUF) * 16384 + (H) * 8192 + wave * 512]); \
        GL_LDS((PTR) + (H) * row128 + row64, &sBf[(BUF) * 16384 + (H) * 8192 + (8 + wave) * 512]); \
    } while (0)

    // ---- fragment read bases (element offsets) ----
    const int fr = lane & 15;
    const int kq = lane >> 4;
    const int st0 = kq ^ (fr & 7);
    const int st1 = (4 + kq) ^ (fr & 7);
    const int aRd0 = wm * 8192 + fr * 64 + st0 * 8;
    const int aRd1 = wm * 8192 + fr * 64 + st1 * 8;
    const int bRow = (wn & 1) * 64 + fr;
    const int bRd0 = (wn >> 1) * 8192 + bRow * 64 + st0 * 8;
    const int bRd1 = (wn >> 1) * 8192 + bRow * 64 + st1 * 8;

#define RD_A(dst, BUF, R0)                                                    \
    do {                                                                      \
        _Pragma("unroll")                                                     \
        for (int mi = 0; mi < 4; ++mi) {                                      \
            dst[mi][0] = *(const short8*)&sAf[(BUF) * 16384 + aRd0 + ((R0) + mi * 16) * 64]; \
            dst[mi][1] = *(const short8*)&sAf[(BUF) * 16384 + aRd1 + ((R0) + mi * 16) * 64]; \
        }                                                                     \
    } while (0)
#define RD_B(dst, BUF, R0)                                                    \
    do {                                                                      \
        _Pragma("unroll")                                                     \
        for (int ni = 0; ni < 2; ++ni) {                                      \
            dst[ni][0] = *(const short8*)&sBf[(BUF) * 16384 + bRd0 + ((R0) + ni * 16) * 64]; \
            dst[ni][1] = *(const short8*)&sBf[(BUF) * 16384 + bRd1 + ((R0) + ni * 16) * 64]; \
        }                                                                     \
    } while (0)
#define MFMA_PH(AF, RB, BF, CB)                                               \
    do {                                                                      \
        _Pragma("unroll")                                                     \
        for (int kh = 0; kh < 2; ++kh)                                        \
            _Pragma("unroll")                                                 \
            for (int mi = 0; mi < 4; ++mi)                                    \
                _Pragma("unroll")                                             \
                for (int ni = 0; ni < 2; ++ni)                                \
                    acc[(RB) + mi][(CB) + ni] =                               \
                        __builtin_amdgcn_mfma_f32_16x16x32_bf16(              \
                            AF[mi][kh], BF[ni][kh],                           \
                            acc[(RB) + mi][(CB) + ni], 0, 0, 0);              \
    } while (0)

    floatx4 acc[8][4];
#pragma unroll
    for (int i = 0; i < 8; ++i)
#pragma unroll
        for (int j = 0; j < 4; ++j) acc[i][j] = (floatx4){0.f, 0.f, 0.f, 0.f};

    short8 afX[4][2], afY[4][2], bf01[2][2], bf23[2][2];

    // ---- prologue: stage A(0),B(0),B(1); vmcnt(4) leaves B(1) in flight ----
    {
        const u16* a0 = aStage - 64;
        const u16* b0 = bStage - 128;
        STAGE_A(0, 0, a0);
        STAGE_A(0, 1, a0);
        STAGE_B(0, 0, b0);
        STAGE_B(0, 1, b0);
        STAGE_B(1, 0, b0 + 64);
        STAGE_B(1, 1, b0 + 64);
    }
    VMC4();
    BAR();
    RD_A(afX, 0, 0);
    RD_B(bf01, 0, 0);
    SB0();

// TILE body; CUR/NXT compile-time via x2 unroll.
#define TILE(CUR, NXT)                                                        \
    /* ph1: MFMA (qm0,n01); read bf23(cur); stage A0(t+1) */                  \
    LGKM0();                                                                  \
    PRIO1();                                                                  \
    MFMA_PH(afX, 0, bf01, 0);                                                 \
    PRIO0();                                                                  \
    SB0();                                                                    \
    RD_B(bf23, CUR, 32);                                                      \
    STAGE_A(NXT, 0, aStage);                                                  \
    SB0();                                                                    \
    /* ph2: MFMA (qm0,n23); read afY(cur); stage A1(t+1); mid sync */         \
    LGKM0();                                                                  \
    PRIO1();                                                                  \
    MFMA_PH(afX, 0, bf23, 2);                                                 \
    PRIO0();                                                                  \
    SB0();                                                                    \
    RD_A(afY, CUR, 64);                                                       \
    STAGE_A(NXT, 1, aStage);                                                  \
    VMC4(); /* B(t+1) landed */                                               \
    BAR();                                                                    \
    /* ph3: MFMA (qm1,n01); read bf01'(nxt); stage B0(t+2) */                 \
    LGKM0();                                                                  \
    PRIO1();                                                                  \
    MFMA_PH(afY, 4, bf01, 0);                                                 \
    PRIO0();                                                                  \
    SB0();                                                                    \
    RD_B(bf01, NXT, 0);                                                       \
    STAGE_B(CUR, 0, bStage);                                                  \
    SB0();                                                                    \
    /* ph4: MFMA (qm1,n23); stage B1(t+2); end sync; read afX'(nxt) */        \
    PRIO1();                                                                  \
    MFMA_PH(afY, 4, bf23, 2);                                                 \
    PRIO0();                                                                  \
    SB0();                                                                    \
    STAGE_B(CUR, 1, bStage);                                                  \
    VMC4(); /* A(t+1) landed */                                               \
    BAR();                                                                    \
    RD_A(afX, NXT, 0);                                                        \
    SB0();                                                                    \
    aStage += 64;                                                             \
    bStage += 64;

    const int NT = K >> 6;  // even (16 here)
    for (int t = 0; t < NT; t += 2) {
        TILE(0, 1)
        TILE(1, 0)
    }
#undef TILE

    // epilogue: C/D 16x16 layout: col = lane&15, row = (lane>>4)*4 + r
    const int cc = lane & 15;
    const int rb = (lane >> 4) * 4;
#pragma unroll
    for (int mi = 0; mi < 8; ++mi)
#pragma unroll
        for (int ni = 0; ni < 4; ++ni)
#pragma unroll
            for (int r = 0; r < 4; ++r) {
                int grow = bm + wm * 128 + mi * 16 + rb + r;
                int gcol = bn + wn * 64 + ni * 16 + cc;
                float v = acc[mi][ni][r];
                if (OUT_BF16)
                    ((u16*)Cout)[(size_t)grow * N + gcol] = f2bf(v);
                else
                    ((float*)Cout)[(size_t)grow * N + gcol] = v;
            }
#undef STAGE_A
#undef STAGE_B
#undef RD_A
#undef RD_B
#undef MFMA_PH
}

// ---------------------------------------------------------------------------
// 128x128 GEMM (C = A @ B^T), same pipelined schedule at 128-tile for the
// thin out-proj (N=1024 -> 512 blocks, full chip). BK=64, 8 waves (2M x 4N),
// per-wave C = 64x32 (4x2 16x16x32 frags). LDS 64 KiB dbuf -> 2 blocks/CU
// (4 waves/SIMD). 2 phases/tile, 2 barriers, counted vmcnt(2):
//   train: A(t+1) staged at ph1, B(t+2) at ph2. At ph2-end vmcnt(2) leaves
//   only B(t+2) in flight => A(t+1),B(t+1) landed for the tile-end reads.
// ph1-end barrier guards the STAGE_B(CUR) WAR (all waves drained their
// cur-B reads via ph1's lgkm0 before any wave's ph2 STAGE_B issues).
// Stage pointers overrun K-end by <=2 tiles into the following allocation
// (ysk->float bufs, owb->wsb; both readable), landing in a dead LDS buffer.
// ---------------------------------------------------------------------------
template <int OUT_BF16>
__global__ __launch_bounds__(512, 4) void gemm_bt_128p(
    const u16* __restrict__ A, const u16* __restrict__ B,
    void* __restrict__ Cout, int N, int K) {
    __shared__ u16 sAf[2 * 128 * 64];   // [buf][row*64 + slot*8]
    __shared__ u16 sBf[2 * 128 * 64];
    const int tid = threadIdx.x;
    const int lane = tid & 63;
    const int wave = tid >> 6;   // 0..7
    const int wm = wave >> 2;    // 0..1  (M half: 64 rows)
    const int wn = wave & 3;     // 0..3  (N quarter: 32 cols)

    const int gx = gridDim.x;
    const int nwg = gx * gridDim.y;
    const int cpx = nwg >> 3;                       // nwg % 8 == 0 here
    int lin = blockIdx.y * gx + blockIdx.x;
    int swz = (lin & 7) * cpx + (lin >> 3);
    const int bm = (swz / gx) * 128;
    const int bn = (swz % gx) * 128;

    const int gslot = (lane & 7) ^ ((lane >> 3) & 7);
    const int srowoff = lane >> 3;                  // 0..7
    const u16* aStage = A + (size_t)(bm + wave * 8 + srowoff) * K + gslot * 8 + 64;
    const u16* bStage = B + (size_t)(bn + wave * 8 + srowoff) * K + gslot * 8 + 128;
    const size_t row64 = (size_t)64 * K;

#define STAGE_A(BUF, PTR)                                                     \
    do {                                                                      \
        GL_LDS((PTR),         &sAf[(BUF) * 8192 + wave * 512]);               \
        GL_LDS((PTR) + row64, &sAf[(BUF) * 8192 + (8 + wave) * 512]);         \
    } while (0)
#define STAGE_B(BUF, PTR)                                                     \
    do {                                                                      \
        GL_LDS((PTR),         &sBf[(BUF) * 8192 + wave * 512]);               \
        GL_LDS((PTR) + row64, &sBf[(BUF) * 8192 + (8 + wave) * 512]);         \
    } while (0)

    // fragment bases: stored slot = g ^ (row&7); row bases are mult of 8.
    const int fr = lane & 15;
    const int kq = lane >> 4;
    const int st0 = kq ^ (fr & 7);
    const int st1 = (4 + kq) ^ (fr & 7);
    const int aRd0 = (wm * 64 + fr) * 64 + st0 * 8;
    const int aRd1 = (wm * 64 + fr) * 64 + st1 * 8;
    const int bRd0 = (wn * 32 + fr) * 64 + st0 * 8;
    const int bRd1 = (wn * 32 + fr) * 64 + st1 * 8;

#define RD_A(dst, BUF)                                                        \
    do {                                                                      \
        _Pragma("unroll")                                                     \
        for (int mi = 0; mi < 4; ++mi) {                                      \
            dst[mi][0] = *(const short8*)&sAf[(BUF) * 8192 + aRd0 + mi * 16 * 64]; \
            dst[mi][1] = *(const short8*)&sAf[(BUF) * 8192 + aRd1 + mi * 16 * 64]; \
        }                                                                     \
    } while (0)
#define RD_B(dst, BUF, NI)                                                    \
    do {                                                                      \
        dst[0] = *(const short8*)&sBf[(BUF) * 8192 + bRd0 + (NI) * 16 * 64];  \
        dst[1] = *(const short8*)&sBf[(BUF) * 8192 + bRd1 + (NI) * 16 * 64];  \
    } while (0)
#define MFMA8(BF, NI)                                                         \
    do {                                                                      \
        _Pragma("unroll")                                                     \
        for (int kh = 0; kh < 2; ++kh)                                        \
            _Pragma("unroll")                                                 \
            for (int mi = 0; mi < 4; ++mi)                                    \
                acc[mi][NI] = __builtin_amdgcn_mfma_f32_16x16x32_bf16(        \
                    afc[mi][kh], BF[kh], acc[mi][NI], 0, 0, 0);               \
    } while (0)

    floatx4 acc[4][2];
#pragma unroll
    for (int i = 0; i < 4; ++i)
#pragma unroll
        for (int j = 0; j < 2; ++j) acc[i][j] = (floatx4){0.f, 0.f, 0.f, 0.f};

    short8 afc[4][2], bf0[2], bf1[2];

    // prologue: A(0),B(0) landed; B(1) stays in flight.
    STAGE_A(0, aStage - 64);
    STAGE_B(0, bStage - 128);
    STAGE_B(1, bStage - 64);
    VMC2();
    BAR();
    RD_A(afc, 0);
    RD_B(bf0, 0, 0);
    SB0();

#define TILE(CUR, NXT)                                                        \
    /* ph1: MFMA ni0; read bf1(cur); stage A(t+1) */                          \
    LGKM0();                                                                  \
    PRIO1();                                                                  \
    MFMA8(bf0, 0);                                                            \
    PRIO0();                                                                  \
    SB0();                                                                    \
    RD_B(bf1, CUR, 1);                                                        \
    STAGE_A(NXT, aStage);                                                     \
    BAR();                                                                    \
    /* ph2: MFMA ni1; stage B(t+2); end sync; read next frags */              \
    LGKM0();                                                                  \
    PRIO1();                                                                  \
    MFMA8(bf1, 1);                                                            \
    PRIO0();                                                                  \
    SB0();                                                                    \
    STAGE_B(CUR, bStage);                                                     \
    VMC2(); /* A(t+1), B(t+1) landed; B(t+2) in flight */                     \
    BAR();                                                                    \
    RD_A(afc, NXT);                                                           \
    RD_B(bf0, NXT, 0);                                                        \
    SB0();                                                                    \
    aStage += 64;                                                             \
    bStage += 64;

    const int NT = K >> 6;  // 32 here (even)
    for (int t = 0; t < NT; t += 2) {
        TILE(0, 1)
        TILE(1, 0)
    }
#undef TILE

    asm volatile("s_waitcnt vmcnt(0)" ::: "memory");  // drain overrun stages

    // epilogue: C/D 16x16 layout: col = lane&15, row = (lane>>4)*4 + r
    const int cc = lane & 15;
    const int rb = (lane >> 4) * 4;
#pragma unroll
    for (int mi = 0; mi < 4; ++mi)
#pragma unroll
        for (int ni = 0; ni < 2; ++ni)
#pragma unroll
            for (int r = 0; r < 4; ++r) {
                int grow = bm + wm * 64 + mi * 16 + rb + r;
                int gcol = bn + wn * 32 + ni * 16 + cc;
                float v = acc[mi][ni][r];
                if (OUT_BF16)
                    ((u16*)Cout)[(size_t)grow * N + gcol] = f2bf(v);
                else
                    ((float*)Cout)[(size_t)grow * N + gcol] = v;
            }
#undef STAGE_A
#undef STAGE_B
#undef RD_A
#undef RD_B
#undef MFMA8
}

// depthwise causal conv (DC=4) + bias + silu + row-mean.
__global__ __launch_bounds__(256) void conv_silu_avg(
    const u16* __restrict__ xin, const float* __restrict__ cw,
    const float* __restrict__ cb, u16* __restrict__ xconv,
    float* __restrict__ xavg) {
    const int blk = blockIdx.x;        // 512 blocks
    const int b = blk >> 7;
    const int lc = blk & 127;
    const int row0 = b * LL + lc * 16;
    const int tid = threadIdx.x;
    const int lane = tid & 63, wave = tid >> 6;
    const int d0 = tid * 8;
    float4 cwv[8];
    float cbv[8];
#pragma unroll
    for (int e = 0; e < 8; ++e) cwv[e] = *(const float4*)&cw[(d0 + e) * 4];
#pragma unroll
    for (int e = 0; e < 8; e += 4) {
        float4 c = *(const float4*)&cb[d0 + e];
        cbv[e] = c.x; cbv[e + 1] = c.y; cbv[e + 2] = c.z; cbv[e + 3] = c.w;
    }
    u16x8 w0, w1, w2;
    if (lc == 0) {
        w0 = (u16x8)0; w1 = (u16x8)0; w2 = (u16x8)0;
    } else {
        w0 = *(const u16x8*)&xin[(size_t)(row0 - 3) * (2 * DINNER) + d0];
        w1 = *(const u16x8*)&xin[(size_t)(row0 - 2) * (2 * DINNER) + d0];
        w2 = *(const u16x8*)&xin[(size_t)(row0 - 1) * (2 * DINNER) + d0];
    }
    float sums[16];
#pragma unroll
    for (int t = 0; t < 16; ++t) {
        u16x8 cur = *(const u16x8*)&xin[(size_t)(row0 + t) * (2 * DINNER) + d0];
        float lsum = 0.f;
        u16x8 o;
#pragma unroll
        for (int e = 0; e < 8; ++e) {
            float acc = cbv[e];
            acc += bf2f(w0[e]) * cwv[e].x;
            acc += bf2f(w1[e]) * cwv[e].y;
            acc += bf2f(w2[e]) * cwv[e].z;
            acc += bf2f(cur[e]) * cwv[e].w;
            float s = silu_f(acc);
            lsum += s;
            o[e] = f2bf(s);
        }
        *(u16x8*)&xconv[(size_t)(row0 + t) * DINNER + d0] = o;
        sums[t] = lsum;
        w0 = w1; w1 = w2; w2 = cur;
    }
#pragma unroll
    for (int off = 32; off; off >>= 1)
#pragma unroll
        for (int t = 0; t < 16; ++t) sums[t] += __shfl_down(sums[t], off);
    __shared__ float wred[4][16];
    if (lane == 0) {
#pragma unroll
        for (int t = 0; t < 16; ++t) wred[wave][t] = sums[t];
    }
    __syncthreads();
    if (tid < 16)
        xavg[row0 + tid] = (wred[0][tid] + wred[1][tid] + wred[2][tid] + wred[3][tid]) *
                           (1.f / DINNER);
}

// delta/B/C projections: thin GEMM (8192 x 48 x 2048), K split across waves.
__global__ __launch_bounds__(256) void dbc_direct(
    const u16* __restrict__ xconv, const u16* __restrict__ wcat,
    const float* __restrict__ db, const float* __restrict__ A_log,
    const float* __restrict__ xavg,
    float* __restrict__ a_out, float* __restrict__ u_out, float* __restrict__ c_out) {
    __shared__ float part[4][32][48];
    const int tid = threadIdx.x;
    const int lane = tid & 63;
    const int wave = tid >> 6;
    const int bm = blockIdx.x * 32;
    const int fr = lane & 15;
    const int kq = lane >> 4;
    const int k0 = wave * 512 + kq * 8;

    const u16* ap0 = xconv + (size_t)(bm + fr) * DINNER + k0;
    const u16* ap1 = xconv + (size_t)(bm + 16 + fr) * DINNER + k0;
    const u16* bp0 = wcat + (size_t)(fr) * DINNER + k0;
    const u16* bp1 = wcat + (size_t)(16 + fr) * DINNER + k0;
    const u16* bp2 = wcat + (size_t)(32 + fr) * DINNER + k0;

    floatx4 acc[2][3];
#pragma unroll
    for (int mi = 0; mi < 2; ++mi)
#pragma unroll
        for (int ni = 0; ni < 3; ++ni) acc[mi][ni] = (floatx4){0.f, 0.f, 0.f, 0.f};

#pragma unroll 4
    for (int kk = 0; kk < 16; ++kk) {
        short8 a0 = *(const short8*)ap0;
        short8 a1 = *(const short8*)ap1;
        short8 b0 = *(const short8*)bp0;
        short8 b1 = *(const short8*)bp1;
        short8 b2 = *(const short8*)bp2;
        ap0 += 32; ap1 += 32; bp0 += 32; bp1 += 32; bp2 += 32;
        acc[0][0] = __builtin_amdgcn_mfma_f32_16x16x32_bf16(a0, b0, acc[0][0], 0, 0, 0);
        acc[0][1] = __builtin_amdgcn_mfma_f32_16x16x32_bf16(a0, b1, acc[0][1], 0, 0, 0);
        acc[0][2] = __builtin_amdgcn_mfma_f32_16x16x32_bf16(a0, b2, acc[0][2], 0, 0, 0);
        acc[1][0] = __builtin_amdgcn_mfma_f32_16x16x32_bf16(a1, b0, acc[1][0], 0, 0, 0);
        acc[1][1] = __builtin_amdgcn_mfma_f32_16x16x32_bf16(a1, b1, acc[1][1], 0, 0, 0);
        acc[1][2] = __builtin_amdgcn_mfma_f32_16x16x32_bf16(a1, b2, acc[1][2], 0, 0, 0);
    }
    // C/D 16x16 layout: col = lane&15, row = (lane>>4)*4 + r
    const int cr = kq * 4;
#pragma unroll
    for (int mi = 0; mi < 2; ++mi)
#pragma unroll
        for (int ni = 0; ni < 3; ++ni)
#pragma unroll
            for (int r = 0; r < 4; ++r)
                part[wave][mi * 16 + cr + r][ni * 16 + fr] = acc[mi][ni][r];
    __syncthreads();
#pragma unroll
    for (int it = tid; it < 512; it += 256) {
        int row = it >> 4;
        int s = it & 15;
        float sd = 0.f, sb = 0.f, sc = 0.f;
#pragma unroll
        for (int w = 0; w < 4; ++w) {
            sd += part[w][row][s];
            sb += part[w][row][s + 16];
            sc += part[w][row][s + 32];
        }
        int grow = bm + row;
        float Aa = -__expf(A_log[s]);
        float pre = sd + db[s];
        float delta = (pre > 20.f) ? pre : log1pf(__expf(pre));
        a_out[grow * NSTATE + s] = __expf(delta * Aa);
        u_out[grow * NSTATE + s] = delta * sb * xavg[grow];
        c_out[grow * NSTATE + s] = sc;
    }
}

// ---- fused parallel linear scan: one kernel, 4 blocks (one per batch) ----
__global__ __launch_bounds__(1024) void scan_fused(
    const float* __restrict__ a, const float* __restrict__ u,
    const float* __restrict__ c, float* __restrict__ y) {
    const int b = blockIdx.x;
    const int tid = threadIdx.x;
    const int s = tid & 15;
    const int seg = tid >> 4;   // 0..63
    __shared__ float Ps[NSEG][NSTATE];
    __shared__ float Hs[NSEG][NSTATE];
    __shared__ float HSs[NSEG][NSTATE];

    size_t base = (size_t)(b * LL + seg * SEGLEN) * NSTATE + s;
    float P = 1.f, h = 0.f;
#pragma unroll 8
    for (int t = 0; t < SEGLEN; ++t) {
        float av = a[base + (size_t)t * NSTATE];
        float uv = u[base + (size_t)t * NSTATE];
        h = fmaf(av, h, uv);
        P *= av;
    }
    Ps[seg][s] = P;
    Hs[seg][s] = h;
    __syncthreads();
    if (tid < 16) {
        float hh = 0.f;
        for (int g = 0; g < NSEG; ++g) {
            HSs[g][tid] = hh;
            hh = fmaf(Ps[g][tid], hh, Hs[g][tid]);
        }
    }
    __syncthreads();
    float h2 = HSs[seg][s];
#pragma unroll 8
    for (int t = 0; t < SEGLEN; ++t) {
        float av = a[base + (size_t)t * NSTATE];
        float uv = u[base + (size_t)t * NSTATE];
        float cv = c[base + (size_t)t * NSTATE];
        h2 = fmaf(av, h2, uv);
        float p = h2 * cv;
        p += __shfl_xor(p, 1);
        p += __shfl_xor(p, 2);
        p += __shfl_xor(p, 4);
        p += __shfl_xor(p, 8);
        if (s == 0) y[b * LL + seg * SEGLEN + t] = p;
    }
}

// y_skip = y*silu(x_gate) + x_conv*D  -> bf16
__global__ __launch_bounds__(256) void gate_skip(
    const u16* __restrict__ xin, const float* __restrict__ y,
    const float* __restrict__ Dv, const u16* __restrict__ xconv,
    u16* __restrict__ yskip) {
    size_t i = ((size_t)blockIdx.x * 256 + threadIdx.x) * 8;
    int row = (int)(i >> 11);
    int d = (int)(i & (DINNER - 1));
    u16x8 g = *(const u16x8*)&xin[(size_t)row * (2 * DINNER) + DINNER + d];
    u16x8 xc = *(const u16x8*)&xconv[i];
    float yv = y[row];
    u16x8 o;
#pragma unroll
    for (int e = 0; e < 8; ++e) {
        float gv = silu_f(bf2f(g[e]));
        float v = yv * gv + bf2f(xc[e]) * Dv[d + e];
        o[e] = f2bf(v);
    }
    *(u16x8*)&yskip[i] = o;
}

extern "C" void kernel_launch(void* const* d_in, const int* in_sizes, int n_in,
                              void* d_out, int out_size, void* d_ws, size_t ws_size,
                              hipStream_t stream) {
    const float* x       = (const float*)d_in[0];
    const float* w_in    = (const float*)d_in[1];
    const float* conv_w  = (const float*)d_in[2];
    const float* conv_b  = (const float*)d_in[3];
    const float* A_log   = (const float*)d_in[4];
    const float* Dv      = (const float*)d_in[5];
    const float* delta_w = (const float*)d_in[6];
    const float* delta_b = (const float*)d_in[7];
    const float* B_w     = (const float*)d_in[8];
    const float* C_w     = (const float*)d_in[9];
    const float* out_w   = (const float*)d_in[10];
    float* out = (float*)d_out;

    u16* xb  = (u16*)d_ws;                 // 8192*1024
    u16* wb  = xb + 8388608;               // 4096*1024
    u16* owb = wb + 4194304;               // 1024*2048
    u16* wsb = owb + 2097152;              // 48*2048 (concat dw,bw,cw)
    u16* xin = wsb + 98304;                // 8192*4096
    u16* xcv = xin + 33554432;             // 8192*2048
    u16* ysk = xcv + 16777216;             // 8192*2048
    float* fb     = (float*)(ysk + 16777216);
    float* abuf   = fb;                    // 8192*16
    float* ubuf   = abuf + 131072;
    float* cbuf   = ubuf + 131072;
    float* ybuf   = cbuf + 131072;         // 8192
    float* avgbuf = ybuf + 8192;           // 8192

    cvt_multi<<<7216, 256, 0, stream>>>(x, w_in, out_w, delta_w, B_w, C_w,
                                        xb, wb, owb, wsb, wsb + 32768, wsb + 65536);

    // x_inner = x @ in_proj_w.T : (8192x1024)@(4096x1024)^T -> bf16
    gemm_bt_256<1><<<dim3(16, 32), 512, 0, stream>>>(xb, wb, xin, 2 * DINNER, DMODEL);

    conv_silu_avg<<<512, 256, 0, stream>>>(xin, conv_w, conv_b, xcv, avgbuf);
    dbc_direct<<<256, 256, 0, stream>>>(xcv, wsb, delta_b, A_log, avgbuf,
                                        abuf, ubuf, cbuf);

    scan_fused<<<4, 1024, 0, stream>>>(abuf, ubuf, cbuf, ybuf);

    gate_skip<<<NROW * DINNER / 8 / 256, 256, 0, stream>>>(xin, ybuf, Dv, xcv, ysk);

    // out = y_skip @ out_proj_w.T : (8192x2048)@(1024x2048)^T -> fp32
    gemm_bt_128p<0><<<dim3(8, 64), 512, 0, stream>>>(ysk, owb, out, DMODEL, DINNER);
}